// Round 6
// baseline (128.700 us; speedup 1.0000x reference)
//
#include <hip/hip_runtime.h>

// logits = relu(T1[q] + sum_s T2[t_s]) @ W2^T + b2, vocab=64 so layer-1 is
// 9 table-row gathers from LDS-resident fp16 tables.
//
// R5: single fused kernel, ZERO workspace use.
//  - The harness re-poisons d_ws every timed iteration (the ~43 us 256 MiB
//    fillBufferAligned dispatches dominating every profile). The tables are
//    the only reason ws existed -> each block now builds the 128x64 fp16
//    table in its prologue via MFMA: T = E(64x64) @ W1half^T(64x64) per
//    half = 16 mfma_16x16x32_f16 per wave. b1 folds into the accumulator
//    init, the 1/8 mean folds into 4 muls on the h=1 tiles. W1/embed/b1
//    loads are L2-hot (every block reads the same 48 KB).
//  - prep_kernel deleted; no prep->lru serialization, no ws round-trip.
//  - Fragment convention copied from the verified main loop: D[m][n] with
//    m = (lane>>4)*4+r <- first operand's l15-row, n = lane&15 <- second
//    operand's l15-row. Table build: first = E-frag (rows t), second =
//    W1-frag (rows j) -> lane writes T[tbase+qd*4+r][nt*16+l15], b16 LDS
//    writes into the same 36-dword-stride layout the gather loop reads.
//  - Main loop unchanged from R4: dedup per-lane token loads, packed-token
//    shfl broadcast, fp16 v_pk_add gather-accumulate, operand-swapped
//    MFMA, direct coalesced nontemporal dwordx4 stores.

#define RSTRIDE_W 36                    // dwords per LDS row (32 data + 4 pad)
#define RSTRIDE_H 72                    // halves per LDS row
#define T2_OFF_W  (64 * RSTRIDE_W)      // 2304 dwords
#define LDS_DW    (2 * 64 * RSTRIDE_W)  // 4608 dwords = 18432 B

typedef __attribute__((ext_vector_type(4))) float    f32x4;
typedef __attribute__((ext_vector_type(4))) int      i32x4;
typedef __attribute__((ext_vector_type(8))) _Float16 f16x8;

// load 8 consecutive floats, convert to fp16 fragment
__device__ __forceinline__ f16x8 cvt8(const float* p) {
  f32x4 w0 = *(const f32x4*)p;
  f32x4 w1 = *(const f32x4*)(p + 4);
  f16x8 f;
  f[0] = (_Float16)w0[0]; f[1] = (_Float16)w0[1];
  f[2] = (_Float16)w0[2]; f[3] = (_Float16)w0[3];
  f[4] = (_Float16)w1[0]; f[5] = (_Float16)w1[1];
  f[6] = (_Float16)w1[2]; f[7] = (_Float16)w1[3];
  return f;
}

// 1024 blocks x 256 threads; block owns 256 elements (wave: 4 iters x 16).
__global__ __launch_bounds__(256, 4) void lru_kernel(
    const int*   __restrict__ seqs,
    const int*   __restrict__ qtok,
    const float* __restrict__ embed,
    const float* __restrict__ W1,
    const float* __restrict__ b1,
    const float* __restrict__ W2,
    const float* __restrict__ b2,
    float*       __restrict__ out) {
  __shared__ __align__(16) unsigned lds[LDS_DW];
  const int tid  = threadIdx.x;
  const int lane = tid & 63;
  const int wv   = tid >> 6;
  const int qd   = lane >> 4;
  const int l15  = lane & 15;

  // ---- issue token loads first (HBM latency hides under table build) ----
  const int wbase  = blockIdx.x * 256 + wv * 64;
  const int myelem = wbase + lane;
  const int* srow  = seqs + myelem * 24;
  const i32x4 t0 = __builtin_nontemporal_load((const i32x4*)(srow + 12));
  const i32x4 t1 = __builtin_nontemporal_load((const i32x4*)(srow + 16));
  const i32x4 t2 = __builtin_nontemporal_load((const i32x4*)(srow + 20));
  const int   tq = __builtin_nontemporal_load(qtok + myelem);

  // ---- in-block table build: wave wv computes tokens tbase..tbase+15 ----
  // T1[t][j] = sum_k E[t][k] W1[j][k]       + b1[j]   (h = 0)
  // T2[t][j] = sum_k E[t][k] W1[j][64 + k]  * 0.125   (h = 1)
  {
    const int tbase = wv * 16;
    // A-fragments: E[tbase + l15][ks*32 + qd*8 .. +7]
    const float* er = embed + (tbase + l15) * 64 + qd * 8;
    const f16x8 ea0 = cvt8(er);
    const f16x8 ea1 = cvt8(er + 32);
#pragma unroll
    for (int h = 0; h < 2; ++h) {
#pragma unroll
      for (int nt = 0; nt < 4; ++nt) {
        // B-fragments: W1[j = nt*16 + l15][h*64 + ks*32 + qd*8 .. +7]
        const float* wr = W1 + (nt * 16 + l15) * 128 + h * 64 + qd * 8;
        const f16x8 wb0 = cvt8(wr);
        const f16x8 wb1 = cvt8(wr + 32);
        const float binit = h ? 0.f : b1[nt * 16 + l15];
        f32x4 a;
        a[0] = binit; a[1] = binit; a[2] = binit; a[3] = binit;
        a = __builtin_amdgcn_mfma_f32_16x16x32_f16(ea0, wb0, a, 0, 0, 0);
        a = __builtin_amdgcn_mfma_f32_16x16x32_f16(ea1, wb1, a, 0, 0, 0);
        // lane holds T[h][tbase + qd*4 + r][nt*16 + l15]
        _Float16* trow =
            (_Float16*)lds + (size_t)(h * 64 + tbase + qd * 4) * RSTRIDE_H +
            nt * 16 + l15;
#pragma unroll
        for (int r = 0; r < 4; ++r)
          trow[(size_t)r * RSTRIDE_H] =
              (_Float16)(h ? a[r] * 0.125f : a[r]);
      }
    }
  }

  // ---- W2 A-operand fragments (fp32 global -> fp16) + bias vectors ----
  f16x8 afW[4][2];
  f32x4 bb4[4];
#pragma unroll
  for (int nt = 0; nt < 4; ++nt) {
    const float* wr = W2 + (nt * 16 + l15) * 64 + qd * 8;
    afW[nt][0] = cvt8(wr);
    afW[nt][1] = cvt8(wr + 32);
    bb4[nt] = *(const f32x4*)(b2 + nt * 16 + qd * 4);
  }

  // pack this lane's 8 memory tokens into 2 dwords (values < 64)
  const int pk0 = t0.w | (t1.x << 8) | (t1.y << 16) | (t1.z << 24);
  const int pk1 = t1.w | (t2.x << 8) | (t2.y << 16) | (t2.z << 24);
  __syncthreads();

#pragma unroll
  for (int it = 0; it < 4; ++it) {
    const int b0  = wbase + it * 16;
    const int src = it * 16 + l15;   // lane holding this element's tokens

    const int u0 = __shfl(pk0, src);
    const int u1 = __shfl(pk1, src);
    const int qt = __shfl(tq,  src);

    // packed fp16 accumulators: a0 = features qd*8..+7, a1 = 32+qd*8..+7
    f16x8 a0, a1;
    {
      const f16x8* r1 = (const f16x8*)(lds + qt * RSTRIDE_W + qd * 4);
      a0 = r1[0];          // dwords [qt*36+qd*4 .. +3]
      a1 = r1[4];          // +16 dwords (ks1 half)
    }
#pragma unroll
    for (int s = 0; s < 4; ++s) {
      const int tk = (u0 >> (8 * s)) & 63;
      const f16x8* r2 =
          (const f16x8*)(lds + T2_OFF_W + tk * RSTRIDE_W + qd * 4);
      a0 += r2[0];
      a1 += r2[4];
    }
#pragma unroll
    for (int s = 0; s < 4; ++s) {
      const int tk = (u1 >> (8 * s)) & 63;
      const f16x8* r2 =
          (const f16x8*)(lds + T2_OFF_W + tk * RSTRIDE_W + qd * 4);
      a0 += r2[0];
      a1 += r2[4];
    }
    const f16x8 z = {(_Float16)0, (_Float16)0, (_Float16)0, (_Float16)0,
                     (_Float16)0, (_Float16)0, (_Float16)0, (_Float16)0};
    const f16x8 afA = __builtin_elementwise_max(a0, z);
    const f16x8 afB = __builtin_elementwise_max(a1, z);

    // operand-swapped MFMA: lane = element b0+l15, regs = logits
    // nt*16 + qd*4 + r -> direct coalesced dwordx4 stores
    float* op = out + (size_t)(b0 + l15) * 64 + qd * 4;
#pragma unroll
    for (int nt = 0; nt < 4; ++nt) {
      f32x4 a = bb4[nt];
      a = __builtin_amdgcn_mfma_f32_16x16x32_f16(afW[nt][0], afA, a, 0, 0, 0);
      a = __builtin_amdgcn_mfma_f32_16x16x32_f16(afW[nt][1], afB, a, 0, 0, 0);
      __builtin_nontemporal_store(a, (f32x4*)(op + nt * 16));
    }
  }
}

extern "C" void kernel_launch(void* const* d_in, const int* in_sizes, int n_in,
                              void* d_out, int out_size, void* d_ws, size_t ws_size,
                              hipStream_t stream) {
  const int*   seqs  = (const int*)d_in[0];
  const int*   qtokp = (const int*)d_in[1];
  const float* embed = (const float*)d_in[2];
  const float* W1    = (const float*)d_in[3];
  const float* b1    = (const float*)d_in[4];
  const float* W2    = (const float*)d_in[5];
  const float* b2    = (const float*)d_in[6];
  float*       outp  = (float*)d_out;

  // d_ws intentionally unused: no workspace -> nothing for the harness to
  // re-poison each iteration (the 43 us 256 MiB fills in every profile).
  (void)d_ws; (void)ws_size;

  lru_kernel<<<dim3(1024), dim3(256), 0, stream>>>(seqs, qtokp, embed, W1, b1,
                                                   W2, b2, outp);
}

// Round 7
// 127.454 us; speedup vs baseline: 1.0098x; 1.0098x over previous
//
#include <hip/hip_runtime.h>

// logits = relu(T1[q] + sum_s T2[t_s]) @ W2^T + b2, vocab=64 so layer-1 is
// 9 table-row gathers from LDS-resident fp16 tables.
//
// R6 = split structure (R4) + occupancy fix:
//  - R5's fused table build reverted: it added ~6-10 us/dispatch (redundant
//    per-block MFMA build + ds_write scatter conflicts) and the ws poison
//    fill turned out to be unconditional, so fusing bought nothing.
//  - Grid 2048 x 2 iters/wave (was 1024 x 4): 8 blocks/CU resident instead
//    of 4. R5's counters showed MfmaUtil 2.3% / VALUBusy 7.6% / HBM 25% /
//    Occupancy 23.7% -> pure latency bound; doubling resident waves is the
//    direct fix. VGPR stays at 64 (measured R5) = 8 waves/SIMD allowed;
//    LDS 18432 B allows 8 blocks.
//  - Wave owns 32 elements: lane (&31) loads its own element's 13 token
//    dwords (upper half-wave duplicates, clamped - no OOB); per iteration
//    3 shfls (pk0,pk1,qt) broadcast from lane it*16+l15.
//  - Token loads issued FIRST (before LDS staging + W2 fragments) so HBM
//    latency hides under the prologue.
//  - Main loop unchanged from R4: fp16 v_pk_add gather-accumulate,
//    operand-swapped MFMA (lane = element, regs = 4 consecutive logits),
//    direct coalesced nontemporal dwordx4 stores.

#define RSTRIDE_W 36                    // dwords per LDS row (32 data + 4 pad)
#define T2_OFF_W  (64 * RSTRIDE_W)      // 2304
#define LDS_DW    (2 * 64 * RSTRIDE_W)  // 4608 dwords = 18432 B

typedef __attribute__((ext_vector_type(4))) float    f32x4;
typedef __attribute__((ext_vector_type(4))) int      i32x4;
typedef __attribute__((ext_vector_type(8))) _Float16 f16x8;

// 32 blocks x 256 threads; job = (half, token) = blockIdx*4 + (tid>>6),
// thread j = output feature. T1 folds b1; T2 folds the 1/8 mean.
__global__ void prep_kernel(const float* __restrict__ embed,
                            const float* __restrict__ W1,
                            const float* __restrict__ b1,
                            unsigned short* __restrict__ T) {
  const int job  = blockIdx.x * 4 + (threadIdx.x >> 6);
  const int j    = threadIdx.x & 63;
  const int t    = job & 63;
  const int half = job >> 6;
  const f32x4* w4 = (const f32x4*)(W1 + j * 128 + half * 64);
  const f32x4* e4 = (const f32x4*)(embed + t * 64);
  float acc = 0.f;
#pragma unroll
  for (int k = 0; k < 16; ++k) {
    f32x4 a = w4[k], b = e4[k];
    acc += a[0] * b[0] + a[1] * b[1] + a[2] * b[2] + a[3] * b[3];
  }
  const float outv = half ? acc * 0.125f : acc + b1[j];
  ((_Float16*)T)[half * (64 * 2 * RSTRIDE_W) + t * (2 * RSTRIDE_W) + j] =
      (_Float16)outv;
}

// 2048 blocks x 256 threads; each wave: 2 iters x 16 elements (one MFMA
// tile each). Lane (qd=lane>>4, l15=lane&15) gathers features qd*8..+7
// (ks0) and 32+qd*8..+7 (ks1) of element b0+l15's 9 table rows as packed
// fp16, accumulates with v_pk_add_f16, ReLUs, then per n-tile
// mfma(W2frag, xfrag) -> lane's acc = 4 consecutive logits -> direct
// dwordx4 store.
__global__ __launch_bounds__(256, 4) void lru_kernel(
    const int*      __restrict__ seqs,
    const int*      __restrict__ qtok,
    const float*    __restrict__ W2,
    const float*    __restrict__ b2,
    const unsigned* __restrict__ T,
    float*          __restrict__ out) {
  __shared__ __align__(16) unsigned lds[LDS_DW];
  const int tid  = threadIdx.x;
  const int lane = tid & 63;
  const int wv   = tid >> 6;
  const int qd   = lane >> 4;
  const int l15  = lane & 15;

  // ---- token loads first: wave owns 32 elements, lane (&31) owns one ----
  const int wbase  = blockIdx.x * 128 + wv * 32;
  const int myelem = wbase + (lane & 31);
  const int* srow  = seqs + myelem * 24;
  const i32x4 t0 = __builtin_nontemporal_load((const i32x4*)(srow + 12));
  const i32x4 t1 = __builtin_nontemporal_load((const i32x4*)(srow + 16));
  const i32x4 t2 = __builtin_nontemporal_load((const i32x4*)(srow + 20));
  const int   tq = __builtin_nontemporal_load(qtok + myelem);

  {  // stage tables (1152 uint4 = 4*256 + 128)
    const uint4* src = (const uint4*)T;
    uint4*       dst = (uint4*)lds;
#pragma unroll
    for (int r = 0; r < 4; ++r) dst[tid + r * 256] = src[tid + r * 256];
    if (tid < 128) dst[tid + 1024] = src[tid + 1024];
  }

  // A-operand fragments from W2 (fp32 global -> fp16):
  // lane supplies A[m = l15 -> logit nt*16+l15][k = ks*32 + qd*8 + i]
  f16x8 afW[4][2];
  f32x4 bb4[4];
#pragma unroll
  for (int nt = 0; nt < 4; ++nt) {
    const float* wr = W2 + (nt * 16 + l15) * 64 + qd * 8;
#pragma unroll
    for (int ks = 0; ks < 2; ++ks) {
      f32x4 w0 = *(const f32x4*)(wr + ks * 32);
      f32x4 w1 = *(const f32x4*)(wr + ks * 32 + 4);
      f16x8 f;
      f[0] = (_Float16)w0[0]; f[1] = (_Float16)w0[1];
      f[2] = (_Float16)w0[2]; f[3] = (_Float16)w0[3];
      f[4] = (_Float16)w1[0]; f[5] = (_Float16)w1[1];
      f[6] = (_Float16)w1[2]; f[7] = (_Float16)w1[3];
      afW[nt][ks] = f;
    }
    bb4[nt] = *(const f32x4*)(b2 + nt * 16 + qd * 4);
  }

  // pack this lane's 8 memory tokens into 2 dwords (values < 64)
  const int pk0 = t0.w | (t1.x << 8) | (t1.y << 16) | (t1.z << 24);
  const int pk1 = t1.w | (t2.x << 8) | (t2.y << 16) | (t2.z << 24);
  __syncthreads();

#pragma unroll
  for (int it = 0; it < 2; ++it) {
    const int b0  = wbase + it * 16;
    const int src = it * 16 + l15;   // lane holding this element's tokens

    const int u0 = __shfl(pk0, src);
    const int u1 = __shfl(pk1, src);
    const int qt = __shfl(tq,  src);

    // packed fp16 accumulators: a0 = features qd*8..+7, a1 = 32+qd*8..+7
    f16x8 a0, a1;
    {
      const f16x8* r1 = (const f16x8*)(lds + qt * RSTRIDE_W + qd * 4);
      a0 = r1[0];          // dwords [qt*36+qd*4 .. +3]
      a1 = r1[4];          // +16 dwords (ks1 half)
    }
#pragma unroll
    for (int s = 0; s < 4; ++s) {
      const int tk = (u0 >> (8 * s)) & 63;
      const f16x8* r2 =
          (const f16x8*)(lds + T2_OFF_W + tk * RSTRIDE_W + qd * 4);
      a0 += r2[0];
      a1 += r2[4];
    }
#pragma unroll
    for (int s = 0; s < 4; ++s) {
      const int tk = (u1 >> (8 * s)) & 63;
      const f16x8* r2 =
          (const f16x8*)(lds + T2_OFF_W + tk * RSTRIDE_W + qd * 4);
      a0 += r2[0];
      a1 += r2[4];
    }
    const f16x8 z = {(_Float16)0, (_Float16)0, (_Float16)0, (_Float16)0,
                     (_Float16)0, (_Float16)0, (_Float16)0, (_Float16)0};
    const f16x8 afA = __builtin_elementwise_max(a0, z);
    const f16x8 afB = __builtin_elementwise_max(a1, z);

    // operand-swapped MFMA: lane = element b0+l15, regs = logits
    // nt*16 + qd*4 + r -> direct coalesced dwordx4 stores
    float* op = out + (size_t)(b0 + l15) * 64 + qd * 4;
#pragma unroll
    for (int nt = 0; nt < 4; ++nt) {
      f32x4 a = bb4[nt];
      a = __builtin_amdgcn_mfma_f32_16x16x32_f16(afW[nt][0], afA, a, 0, 0, 0);
      a = __builtin_amdgcn_mfma_f32_16x16x32_f16(afW[nt][1], afB, a, 0, 0, 0);
      __builtin_nontemporal_store(a, (f32x4*)(op + nt * 16));
    }
  }
}

extern "C" void kernel_launch(void* const* d_in, const int* in_sizes, int n_in,
                              void* d_out, int out_size, void* d_ws, size_t ws_size,
                              hipStream_t stream) {
  const int*   seqs  = (const int*)d_in[0];
  const int*   qtokp = (const int*)d_in[1];
  const float* embed = (const float*)d_in[2];
  const float* W1    = (const float*)d_in[3];
  const float* b1    = (const float*)d_in[4];
  const float* W2    = (const float*)d_in[5];
  const float* b2    = (const float*)d_in[6];
  float*       outp  = (float*)d_out;

  prep_kernel<<<dim3(32), dim3(256), 0, stream>>>(embed, W1, b1,
                                                  (unsigned short*)d_ws);
  lru_kernel<<<dim3(2048), dim3(256), 0, stream>>>(seqs, qtokp, W2, b2,
                                                   (const unsigned*)d_ws, outp);
}